// Round 1
// baseline (34.455 us; speedup 1.0000x reference)
//
#include <hip/hip_runtime.h>

// JPEGBase: rgb->yuv, *255, blockwise DCT, blockwise IDCT, yuv->rgb, /255.
// D is the orthonormal DCT-II basis, so DCT->IDCT is the identity (exact in
// real arithmetic; ~1e-4 abs rounding at the x255 scale in f32, i.e. ~4e-7
// after /255 -- far below the 2e-2 absmax threshold). The *255 and /255 also
// cancel. So the whole op reduces to the per-pixel color round-trip
// rgb -> yuv -> rgb with the reference coefficients.
//
// Layout (B=32, C=3, H=W=512): channel plane = 512*512 = 262144 floats
// = 65536 float4. Each thread processes one float4 from each of the three
// channel planes of one batch image (coalesced within each plane).

#define P4 65536          // float4 elements per channel plane (512*512/4)
// total float4 groups = B * P4 = 32 * 65536 = 2097152

__global__ __launch_bounds__(256) void jpeg_color_roundtrip(
    const float4* __restrict__ in, float4* __restrict__ out, int total)
{
    int t = blockIdx.x * blockDim.x + threadIdx.x;
    if (t >= total) return;
    int b = t >> 16;            // batch index (P4 = 2^16)
    int p = t & (P4 - 1);       // float4 index within plane
    long base = (long)b * (3 * P4) + p;

    float4 r4 = in[base];
    float4 g4 = in[base + P4];
    float4 b4 = in[base + 2 * P4];

    float4 ro, go, bo;
    float* rp = &r4.x; float* gp = &g4.x; float* bp = &b4.x;
    float* rop = &ro.x; float* gop = &go.x; float* bop = &bo.x;
#pragma unroll
    for (int i = 0; i < 4; ++i) {
        float r = rp[i], g = gp[i], bl = bp[i];
        // rgb -> yuv (reference coefficients)
        float y = 0.299f * r + 0.587f * g + 0.114f * bl;
        float u = -0.147f * r - 0.289f * g + 0.436f * bl;
        float v = 0.615f * r - 0.515f * g - 0.100f * bl;
        // yuv -> rgb
        rop[i] = y + 1.140f * v;
        gop[i] = y - 0.396f * u - 0.581f * v;
        bop[i] = y + 2.029f * u;
    }

    out[base] = ro;
    out[base + P4] = go;
    out[base + 2 * P4] = bo;
}

extern "C" void kernel_launch(void* const* d_in, const int* in_sizes, int n_in,
                              void* d_out, int out_size, void* d_ws, size_t ws_size,
                              hipStream_t stream) {
    // d_in[0] = i_co (UNUSED by the reference), d_in[1] = i_en
    const float4* in = (const float4*)d_in[1];
    float4* out = (float4*)d_out;
    const int total = 32 * P4;  // 2,097,152 float4 groups
    const int block = 256;
    const int grid = (total + block - 1) / block;  // 8192 blocks
    jpeg_color_roundtrip<<<grid, block, 0, stream>>>(in, out, total);
}